// Round 7
// baseline (20400.670 us; speedup 1.0000x reference)
//
#include <hip/hip_runtime.h>
#include <hip/hip_bf16.h>

// Problem constants (MultiHeadAttention: B=4, S=2048, D=1024, H=16, Dk=64)
#define B_SZ 4
#define S_SZ 2048
#define D_SZ 1024
#define H_SZ 16
#define DK_SZ 64
#define M_ROWS (B_SZ * S_SZ)   // 8192

// ---------------------------------------------------------------------------
// NAIVE tiled VALU GEMM: C[M,N] = A[M,K] @ W[N,K]^T + bias[N].
// fp32 LDS + fp32 acc; TA/TW/TC independently float or __bf16.
// 64x64 tile, BK=16, 256 threads, each thread 4x4 outputs.
// ---------------------------------------------------------------------------
#define NTP 17   // +1 padded LDS stride
template <typename TA, typename TW, typename TC>
__global__ __launch_bounds__(256, 2)
void gemm_naive(const TA* __restrict__ A, const TW* __restrict__ W,
                const float* __restrict__ bias, TC* __restrict__ C,
                int M, int N, int K) {
    __shared__ float sA[64][NTP];
    __shared__ float sW[64][NTP];
    const int tid = threadIdx.x;
    const int m0 = blockIdx.x * 64, n0 = blockIdx.y * 64;
    const int tx = tid & 15, ty = tid >> 4;          // output 4x4 sub-tile coords
    const int lrow = tid >> 2, lc4 = (tid & 3) * 4;  // staging assignment

    float acc[4][4] = {};

    for (int kt = 0; kt < K; kt += 16) {
        for (int e = 0; e < 4; ++e) {
            sA[lrow][lc4 + e] = (float)A[(size_t)(m0 + lrow) * K + kt + lc4 + e];
            sW[lrow][lc4 + e] = (float)W[(size_t)(n0 + lrow) * K + kt + lc4 + e];
        }
        __syncthreads();
        for (int k = 0; k < 16; ++k) {
            float a[4], b[4];
            for (int i = 0; i < 4; ++i) a[i] = sA[ty * 4 + i][k];
            for (int j = 0; j < 4; ++j) b[j] = sW[tx * 4 + j][k];
            for (int i = 0; i < 4; ++i)
                for (int j = 0; j < 4; ++j)
                    acc[i][j] += a[i] * b[j];
        }
        __syncthreads();
    }
    for (int i = 0; i < 4; ++i) {
        const int row = m0 + ty * 4 + i;
        for (int j = 0; j < 4; ++j) {
            const int col = n0 + tx * 4 + j;
            C[(size_t)row * N + col] = (TC)(acc[i][j] + bias[col]);
        }
    }
}

// ---------------------------------------------------------------------------
// NAIVE attention: one block per (q_row, b*h). 256 threads. fp32 math.
// Planes (q/k/v/ctx) are TP (float or __bf16), layout [B*S, 1024], head h at
// column h*64. ctx aliases qm: block reads its q row at start, writes the same
// region at end; regions disjoint across blocks -> safe.
// ---------------------------------------------------------------------------
template <typename TP>
__global__ __launch_bounds__(256, 2)
void attn_naive(const TP* qm, const TP* __restrict__ km,
                const TP* __restrict__ vm, TP* ctx) {
    __shared__ float sS[S_SZ];          // scores / weights (8 KB)
    __shared__ float sQ[DK_SZ];         // q row fp32
    __shared__ float sRed[256];         // reductions
    __shared__ float sCtx[4][DK_SZ];    // ctx partials

    const int tid = threadIdx.x;
    const int qrow = blockIdx.x;            // 0..S-1
    const int bh = blockIdx.y;
    const int b = bh >> 4, h = bh & 15;
    const size_t rb = (size_t)b * S_SZ;
    const int hoff = h * DK_SZ;

    if (tid < 64) sQ[tid] = (float)qm[(rb + qrow) * D_SZ + hoff + tid];
    __syncthreads();

    // scores: 8 keys per thread
    for (int jj = 0; jj < 8; ++jj) {
        const int j = tid * 8 + jj;
        const TP* kp = km + (rb + j) * D_SZ + hoff;
        float acc = 0.f;
        for (int e = 0; e < 64; ++e) acc += sQ[e] * (float)kp[e];
        sS[j] = acc * 0.125f;   // 1/sqrt(64)
    }
    __syncthreads();

    // max reduce
    float mx = -1e30f;
    for (int j = tid; j < S_SZ; j += 256) mx = fmaxf(mx, sS[j]);
    sRed[tid] = mx; __syncthreads();
    for (int s = 128; s > 0; s >>= 1) {
        if (tid < s) sRed[tid] = fmaxf(sRed[tid], sRed[tid + s]);
        __syncthreads();
    }
    mx = sRed[0];
    __syncthreads();   // protect sRed before reuse

    // exp + sum
    float sm = 0.f;
    for (int j = tid; j < S_SZ; j += 256) {
        float e = __expf(sS[j] - mx);
        sS[j] = e; sm += e;
    }
    sRed[tid] = sm; __syncthreads();
    for (int s = 128; s > 0; s >>= 1) {
        if (tid < s) sRed[tid] += sRed[tid + s];
        __syncthreads();
    }
    const float inv = 1.f / sRed[0];

    // ctx: thread t owns d = t&63, key subset t>>6 (stride 4)
    const int d = tid & 63, sub = tid >> 6;
    float part = 0.f;
    for (int j = sub; j < S_SZ; j += 4)
        part += sS[j] * (float)vm[(rb + j) * D_SZ + hoff + d];
    sCtx[sub][d] = part;
    __syncthreads();
    if (tid < 64) {
        float v = (sCtx[0][tid] + sCtx[1][tid] + sCtx[2][tid] + sCtx[3][tid]) * inv;
        ctx[(rb + qrow) * D_SZ + hoff + tid] = (TP)v;
    }
}

// ---------------------------------------------------------------------------
extern "C" void kernel_launch(void* const* d_in, const int* in_sizes, int n_in,
                              void* d_out, int out_size, void* d_ws, size_t ws_size,
                              hipStream_t stream) {
    // Inputs fp32 (reference dtype). OUTPUT fp32 (reference returns float32 —
    // this is the round-7 hypothesis fix; we previously wrote bf16).
    const float* Q  = (const float*)d_in[0];
    const float* K  = (const float*)d_in[1];
    const float* V  = (const float*)d_in[2];
    const float* Wq = (const float*)d_in[3];
    const float* bq = (const float*)d_in[4];
    const float* Wk = (const float*)d_in[5];
    const float* bk = (const float*)d_in[6];
    const float* Wv = (const float*)d_in[7];
    const float* bv = (const float*)d_in[8];
    const float* Wo = (const float*)d_in[9];
    const float* bo = (const float*)d_in[10];
    float* out = (float*)d_out;

    const size_t plane = (size_t)M_ROWS * D_SZ;   // 8.4M elems
    dim3 gg(M_ROWS / 64, D_SZ / 64), bb(256);
    dim3 ga(S_SZ, B_SZ * H_SZ);

    if (ws_size >= 3 * plane * sizeof(float)) {
        // fp32 planes: q, k, v in ws; ctx aliases q plane.
        float* qw = (float*)d_ws;
        float* kw = qw + plane;
        float* vw = qw + 2 * plane;
        float* cw = qw;
        gemm_naive<float, float, float><<<gg, bb, 0, stream>>>(Q, Wq, bq, qw, M_ROWS, D_SZ, D_SZ);
        gemm_naive<float, float, float><<<gg, bb, 0, stream>>>(K, Wk, bk, kw, M_ROWS, D_SZ, D_SZ);
        gemm_naive<float, float, float><<<gg, bb, 0, stream>>>(V, Wv, bv, vw, M_ROWS, D_SZ, D_SZ);
        attn_naive<float><<<ga, bb, 0, stream>>>(qw, kw, vw, cw);
        gemm_naive<float, float, float><<<gg, bb, 0, stream>>>(cw, Wo, bo, out, M_ROWS, D_SZ, D_SZ);
    } else {
        // bf16 planes fallback (32 MiB ws): q, k in ws; v in d_out scratch
        // (bf16 16 MiB in a 32 MiB fp32 buffer; final GEMM overwrites d_out
        // after v is consumed). ctx aliases q plane.
        if (ws_size < 2 * plane * sizeof(__bf16)) return;
        __bf16* qw = (__bf16*)d_ws;
        __bf16* kw = qw + plane;
        __bf16* vw = (__bf16*)d_out;
        __bf16* cw = qw;
        gemm_naive<float, float, __bf16><<<gg, bb, 0, stream>>>(Q, Wq, bq, qw, M_ROWS, D_SZ, D_SZ);
        gemm_naive<float, float, __bf16><<<gg, bb, 0, stream>>>(K, Wk, bk, kw, M_ROWS, D_SZ, D_SZ);
        gemm_naive<float, float, __bf16><<<gg, bb, 0, stream>>>(V, Wv, bv, vw, M_ROWS, D_SZ, D_SZ);
        attn_naive<__bf16><<<ga, bb, 0, stream>>>(qw, kw, vw, cw);
        gemm_naive<__bf16, float, float><<<gg, bb, 0, stream>>>(cw, Wo, bo, out, M_ROWS, D_SZ, D_SZ);
    }
}

// Round 8
// 721.747 us; speedup vs baseline: 28.2657x; 28.2657x over previous
//
#include <hip/hip_runtime.h>
#include <hip/hip_bf16.h>

// Problem constants (MultiHeadAttention: B=4, S=2048, D=1024, H=16, Dk=64)
#define B_SZ 4
#define S_SZ 2048
#define D_SZ 1024
#define H_SZ 16
#define DK_SZ 64
#define M_ROWS (B_SZ * S_SZ)   // 8192

typedef __bf16 bf16x8 __attribute__((ext_vector_type(8)));
typedef float  f32x4  __attribute__((ext_vector_type(4)));

// load 8 contiguous elements -> bf16x8 (fp32 source converts during staging)
__device__ __forceinline__ bf16x8 load8(const float* p) {
    f32x4 a = *(const f32x4*)p;
    f32x4 b = *(const f32x4*)(p + 4);
    bf16x8 r;
    r[0] = (__bf16)a[0]; r[1] = (__bf16)a[1]; r[2] = (__bf16)a[2]; r[3] = (__bf16)a[3];
    r[4] = (__bf16)b[0]; r[5] = (__bf16)b[1]; r[6] = (__bf16)b[2]; r[7] = (__bf16)b[3];
    return r;
}
__device__ __forceinline__ bf16x8 load8(const __bf16* p) {
    return *(const bf16x8*)p;
}

// ---------------------------------------------------------------------------
// MFMA GEMM NT + bias: C[M,N] = A[M,K] @ W[N,K]^T + bias[N], fp32 acc.
// TA/TW: float or __bf16 (converted to bf16 at staging). TC: float or __bf16.
// 128x128 tile, BK=64, 4 waves (2x2), each wave 64x64 = 4x4 MFMA 16x16x32.
// LDS padded stride 72 elems (144 B -> adjacent rows shift 4 banks, ~2-way).
// ---------------------------------------------------------------------------
#define SAST 72
template <typename TA, typename TW, typename TC>
__global__ __launch_bounds__(256, 2)
void gemm_nt_bias(const TA* __restrict__ A, const TW* __restrict__ W,
                  const float* __restrict__ bias, TC* __restrict__ C,
                  int M, int N, int K) {
    __shared__ __align__(16) __bf16 sA[128 * SAST];
    __shared__ __align__(16) __bf16 sB[128 * SAST];
    const int tid = threadIdx.x;
    const int w = tid >> 6, lane = tid & 63;
    const int m0 = blockIdx.x * 128, n0 = blockIdx.y * 128;
    const int wr = w >> 1, wc = w & 1;         // wave 2x2 position
    const int lr = lane & 15, lq = lane >> 4;  // frag row, quad

    f32x4 acc[4][4] = {};

    for (int kt = 0; kt < K; kt += 64) {
        for (int it = 0; it < 4; ++it) {
            const int c = it * 256 + tid;          // chunk id
            const int row = c >> 3, col8 = c & 7;  // row 0..127, 8-elem col group
            *(bf16x8*)&sA[row * SAST + col8 * 8] =
                load8(A + (size_t)(m0 + row) * K + kt + col8 * 8);
            *(bf16x8*)&sB[row * SAST + col8 * 8] =
                load8(W + (size_t)(n0 + row) * K + kt + col8 * 8);
        }
        __syncthreads();
        for (int s = 0; s < 2; ++s) {   // two K=32 steps
            bf16x8 av[4], bv[4];
            for (int i = 0; i < 4; ++i)
                av[i] = *(const bf16x8*)&sA[(wr * 64 + i * 16 + lr) * SAST + s * 32 + lq * 8];
            for (int j = 0; j < 4; ++j)
                bv[j] = *(const bf16x8*)&sB[(wc * 64 + j * 16 + lr) * SAST + s * 32 + lq * 8];
            for (int i = 0; i < 4; ++i)
                for (int j = 0; j < 4; ++j)
                    acc[i][j] = __builtin_amdgcn_mfma_f32_16x16x32_bf16(
                        av[i], bv[j], acc[i][j], 0, 0, 0);
        }
        __syncthreads();
    }
    // epilogue: C/D layout row=lq*4+r, col=lr
    for (int j = 0; j < 4; ++j) {
        const int col = n0 + wc * 64 + j * 16 + lr;
        const float bias_f = bias[col];
        for (int i = 0; i < 4; ++i) {
            const int rbase = m0 + wr * 64 + i * 16 + lq * 4;
            for (int r = 0; r < 4; ++r)
                C[(size_t)(rbase + r) * N + col] = (TC)(acc[i][j][r] + bias_f);
        }
    }
}

// ---------------------------------------------------------------------------
// Flash attention: grid (S/64, B*H), block 256 (4 waves).
// Wave w handles 16 query rows; loop over 32-key tiles.
// q,k,v,ctx all [B*S, 1024] bf16, head h at column h*64.
// ctx aliases qm (in-place): each block reads exactly the q region it later
// writes (read at start, write at end; regions disjoint across blocks).
// ---------------------------------------------------------------------------
#define VST 40   // padded LDS stride (elems) for sVt / sP
#define SKST 72  // padded LDS stride for sK
__global__ __launch_bounds__(256, 2)
void attn_kernel(const __bf16* qm, const __bf16* __restrict__ km,
                 const __bf16* __restrict__ vm, __bf16* ctx) {
    __shared__ __align__(16) __bf16 sK[32 * SKST];      // [key][dk]
    __shared__ __align__(16) __bf16 sVt[64 * VST];      // [dk][key] transposed
    __shared__ __align__(16) __bf16 sP[4][16 * VST];    // per-wave P tile [q][key]

    const int tid = threadIdx.x, w = tid >> 6, lane = tid & 63;
    const int lr = lane & 15, lq = lane >> 4;
    const int bh = blockIdx.y;
    const int b = bh >> 4, h = bh & 15;
    const int q0 = blockIdx.x * 64;
    const size_t rowbase = (size_t)b * S_SZ;
    const int hoff = h * DK_SZ;

    // Q A-fragments for this wave's 16 rows (Dk=64 -> 2 ksteps)
    bf16x8 qf[2];
    {
        const __bf16* qp = qm + (rowbase + q0 + w * 16 + lr) * D_SZ + hoff;
        qf[0] = *(const bf16x8*)(qp + lq * 8);
        qf[1] = *(const bf16x8*)(qp + 32 + lq * 8);
    }

    float mrow[4], lrow[4];
    f32x4 o[4] = {};
    for (int r = 0; r < 4; ++r) { mrow[r] = -1e30f; lrow[r] = 0.f; }

    const int skey = tid >> 3, scol8 = tid & 7;       // K/V staging assignment

    for (int k0 = 0; k0 < S_SZ; k0 += 32) {
        // stage K tile (32 keys x 64 dk): 256 chunks of 8 elems, one per thread
        {
            bf16x8 kv = *(const bf16x8*)(km + (rowbase + k0 + skey) * D_SZ + hoff + scol8 * 8);
            *(bf16x8*)&sK[skey * SKST + scol8 * 8] = kv;
        }
        // stage V tile transposed: thread reads 8 contiguous d, scatters to sVt[d][key]
        {
            bf16x8 vv = *(const bf16x8*)(vm + (rowbase + k0 + skey) * D_SZ + hoff + scol8 * 8);
            for (int e = 0; e < 8; ++e)
                sVt[(scol8 * 8 + e) * VST + skey] = vv[e];
        }
        __syncthreads();

        // QK^T: scores[16q x 32key], two 16-key n-tiles
        f32x4 sc[2];
        for (int nt = 0; nt < 2; ++nt) {
            const int row = nt * 16 + lr;   // key index
            bf16x8 kf0 = *(const bf16x8*)&sK[row * SKST + lq * 8];
            bf16x8 kf1 = *(const bf16x8*)&sK[row * SKST + 32 + lq * 8];
            f32x4 z = {};
            z = __builtin_amdgcn_mfma_f32_16x16x32_bf16(qf[0], kf0, z, 0, 0, 0);
            z = __builtin_amdgcn_mfma_f32_16x16x32_bf16(qf[1], kf1, z, 0, 0, 0);
            sc[nt] = z;
        }

        // online softmax (scale = 1/sqrt(64) = 0.125)
        float alpha[4], pv0[4], pv1[4];
        for (int r = 0; r < 4; ++r) {
            float s0 = sc[0][r] * 0.125f, s1 = sc[1][r] * 0.125f;
            float mx = fmaxf(s0, s1);
            for (int msk = 1; msk < 16; msk <<= 1)
                mx = fmaxf(mx, __shfl_xor(mx, msk));
            const float mn = fmaxf(mrow[r], mx);
            alpha[r] = __expf(mrow[r] - mn);
            mrow[r] = mn;
            const float p0 = __expf(s0 - mn), p1 = __expf(s1 - mn);
            pv0[r] = p0; pv1[r] = p1;
            float ls = p0 + p1;
            for (int msk = 1; msk < 16; msk <<= 1)
                ls += __shfl_xor(ls, msk);
            lrow[r] = lrow[r] * alpha[r] + ls;
        }

        // P (C-layout) -> LDS [q][key] so it can re-enter MFMA in A-layout
        for (int r = 0; r < 4; ++r) {
            sP[w][(lq * 4 + r) * VST +  0 + lr] = (__bf16)pv0[r];
            sP[w][(lq * 4 + r) * VST + 16 + lr] = (__bf16)pv1[r];
        }
        __syncthreads();   // P visible

        for (int nt = 0; nt < 4; ++nt)
            for (int r = 0; r < 4; ++r)
                o[nt][r] *= alpha[r];

        // PV: ctx[16q x 64d] += P[16x32] @ V[32x64]
        bf16x8 pf = *(const bf16x8*)&sP[w][lr * VST + lq * 8];
        for (int nt = 0; nt < 4; ++nt) {
            bf16x8 vf = *(const bf16x8*)&sVt[(nt * 16 + lr) * VST + lq * 8];
            o[nt] = __builtin_amdgcn_mfma_f32_16x16x32_bf16(pf, vf, o[nt], 0, 0, 0);
        }
        __syncthreads();   // all waves done with sK/sVt/sP before next stage
    }

    // epilogue: divide by l, write ctx
    for (int nt = 0; nt < 4; ++nt) {
        for (int r = 0; r < 4; ++r) {
            const float val = o[nt][r] / lrow[r];
            const size_t row = rowbase + q0 + w * 16 + lq * 4 + r;
            ctx[row * D_SZ + hoff + nt * 16 + lr] = (__bf16)val;
        }
    }
}

// ---------------------------------------------------------------------------
extern "C" void kernel_launch(void* const* d_in, const int* in_sizes, int n_in,
                              void* d_out, int out_size, void* d_ws, size_t ws_size,
                              hipStream_t stream) {
    // Inputs fp32; OUTPUT fp32 (verified round 7).
    const float* Q  = (const float*)d_in[0];
    const float* K  = (const float*)d_in[1];
    const float* V  = (const float*)d_in[2];
    const float* Wq = (const float*)d_in[3];
    const float* bq = (const float*)d_in[4];
    const float* Wk = (const float*)d_in[5];
    const float* bk = (const float*)d_in[6];
    const float* Wv = (const float*)d_in[7];
    const float* bv = (const float*)d_in[8];
    const float* Wo = (const float*)d_in[9];
    const float* bo = (const float*)d_in[10];
    float* out = (float*)d_out;

    const size_t plane = (size_t)M_ROWS * D_SZ;   // 8.4M elems
    if (ws_size < 2 * plane * sizeof(__bf16)) return;

    // bf16 planes: q,k in ws; v in d_out-as-scratch (d_out is 32 MiB fp32,
    // bf16 v plane = 16 MiB; attention consumes v before the final GEMM
    // overwrites d_out — stream-ordered). ctx in-place over the q plane.
    __bf16* qw = (__bf16*)d_ws;
    __bf16* kw = qw + plane;
    __bf16* vw = (__bf16*)d_out;
    __bf16* cw = qw;

    dim3 gg(M_ROWS / 128, D_SZ / 128), bb(256);
    gemm_nt_bias<float, float, __bf16><<<gg, bb, 0, stream>>>(Q, Wq, bq, qw, M_ROWS, D_SZ, D_SZ);
    gemm_nt_bias<float, float, __bf16><<<gg, bb, 0, stream>>>(K, Wk, bk, kw, M_ROWS, D_SZ, D_SZ);
    gemm_nt_bias<float, float, __bf16><<<gg, bb, 0, stream>>>(V, Wv, bv, vw, M_ROWS, D_SZ, D_SZ);

    attn_kernel<<<dim3(S_SZ / 64, B_SZ * H_SZ), 256, 0, stream>>>(qw, kw, vw, cw);

    gemm_nt_bias<__bf16, float, float><<<gg, bb, 0, stream>>>(cw, Wo, bo, out,
                                                              M_ROWS, D_SZ, D_SZ);
}